// Round 10
// baseline (318.487 us; speedup 1.0000x reference)
//
#include <hip/hip_runtime.h>

typedef __attribute__((ext_vector_type(8))) short short8;
typedef __attribute__((ext_vector_type(4))) float f32x4;
typedef __attribute__((ext_vector_type(2))) float f32x2;

#define NBMAX 512
#define CAP 8192   // per-bucket stage capacity; mean load 4096, sigma ~64

__device__ inline unsigned short f2bf(float f) {
  union { float f; unsigned u; } v; v.f = f;
  unsigned r = v.u + 0x7fffu + ((v.u >> 16) & 1u);
  return (unsigned short)(r >> 16);
}

// packed accumulate: uint4 of 8 bf16 -> 4x f32x2 (v_pk_add_f32)
__device__ inline void addf2(f32x2 (&a)[4], uint4 v) {
  union { uint2 u; f32x2 f; } t;
  t.u.x = v.x << 16; t.u.y = v.x & 0xffff0000u; a[0] += t.f;
  t.u.x = v.y << 16; t.u.y = v.y & 0xffff0000u; a[1] += t.f;
  t.u.x = v.z << 16; t.u.y = v.z & 0xffff0000u; a[2] += t.f;
  t.u.x = v.w << 16; t.u.y = v.w & 0xffff0000u; a[3] += t.f;
}

__device__ inline int load_src(const int* ei, int E, int e, int f64) {
  return f64 ? ei[2 * e] : ei[e];
}
__device__ inline int load_dst(const int* ei, int E, int e, int f64) {
  return f64 ? ei[2 * (E + e)] : ei[E + e];
}

// ---------------- prep: scatter (CSR phase A) + x->bf16 cast + W permute ----------------
// One launch, three block ranges:
//   [0, SB)        : edge scatter into bucket stage (dst>>8 buckets), 4096/block
//   [SB, SB+4)     : one-time W cast+permute into MFMA B-fragment order
//   [SB+4, ...)    : x (f32) -> xb (bf16) streaming cast
// Staged edge PACKED to 4B: (src << 8) | (dst & 255)  [src < 2^24].
// lbase doubles as the append cursor (absolute slot) — one less LDS pass.
__global__ __launch_bounds__(256) void prep(
    const int* __restrict__ ei, int E,
    int* __restrict__ btot, unsigned* __restrict__ stage, int SB,
    const float* __restrict__ x, unsigned short* __restrict__ xb, int n8,
    const float* __restrict__ W1l, const float* __restrict__ W1r,
    const float* __restrict__ W2l, const float* __restrict__ W2r,
    unsigned short* __restrict__ Wp) {
  __shared__ int lcnt[NBMAX];
  __shared__ int lbase[NBMAX];
  __shared__ int sflag;
  const int b = blockIdx.x;
  const int t = threadIdx.x;

  if (b < SB) {
    // ---- scatter (4096 edges per block) ----
    if (t == 0) sflag = 0;
    for (int i = t; i < NBMAX; i += 256) lcnt[i] = 0;
    __syncthreads();
    const int e0 = b * 4096;
    {
      int e = e0 + t;
      int v = (e < E) ? ei[2 * e + 1] : 0;   // in-bounds under both layouts
      if (v) atomicOr(&sflag, 1);
    }
    __syncthreads();
    const int f64 = (sflag == 0) ? 1 : 0;

    unsigned pk[16];
    int bks[16];
#pragma unroll
    for (int i = 0; i < 16; ++i) {
      int e = e0 + i * 256 + t;
      if (e < E) {
        int s = load_src(ei, E, e, f64);
        int d = load_dst(ei, E, e, f64);
        pk[i] = ((unsigned)s << 8) | ((unsigned)d & 255u);
        bks[i] = d >> 8;
        atomicAdd(&lcnt[d >> 8], 1);
      } else {
        bks[i] = -1;
      }
    }
    __syncthreads();
    for (int i = t; i < NBMAX; i += 256) {
      int c = lcnt[i];
      lbase[i] = c ? atomicAdd(&btot[i], c) : 0;
    }
    __syncthreads();
#pragma unroll
    for (int i = 0; i < 16; ++i) {
      int bk = bks[i];
      if (bk >= 0) {
        int r = atomicAdd(&lbase[bk], 1);   // absolute in-bucket slot
        stage[(size_t)bk * CAP + r] = pk[i];
      }
    }
    return;
  }

  if (b < SB + 4) {
    // ---- W cast + permute (grid-invariant, done once) ----
    const int m = b - SB;
    const float* W = (m == 0) ? W1l : (m == 1) ? W1r : (m == 2) ? W2l : W2r;
    unsigned short* dst = Wp + (size_t)m * 16384;
#pragma unroll
    for (int it = 0; it < 8; ++it) {
      int id = it * 256 + t;
      int j = id >> 4;
      int kc = id & 15;
      int s = kc >> 2, q = kc & 3;
      int jt = j >> 4, nn2 = j & 15;
      int c = (s * 8 + jt) * 4 + q;
      const float* src = W + j * 128 + kc * 8;
      union { unsigned short u[8]; uint4 v; } tv;
#pragma unroll
      for (int k = 0; k < 8; ++k) tv.u[k] = f2bf(src[k]);
      *(uint4*)(dst + (c * 16 + nn2) * 8) = tv.v;
    }
    return;
  }

  // ---- x -> bf16 cast ----
  const int cb = b - SB - 4;
  const int nxb = gridDim.x - SB - 4;
  int i = cb * 256 + t;
  const int stride = nxb * 256;
  for (; i < n8; i += stride) {
    float4 v0 = ((const float4*)x)[2 * i];
    float4 v1 = ((const float4*)x)[2 * i + 1];
    union { unsigned short u[8]; uint4 v; } tv;
    tv.u[0] = f2bf(v0.x); tv.u[1] = f2bf(v0.y);
    tv.u[2] = f2bf(v0.z); tv.u[3] = f2bf(v0.w);
    tv.u[4] = f2bf(v1.x); tv.u[5] = f2bf(v1.y);
    tv.u[6] = f2bf(v1.z); tv.u[7] = f2bf(v1.w);
    ((uint4*)xb)[i] = tv.v;
  }
}

// ---------------- CSR build, phase B ----------------
// one WG per bucket: cross-bucket prefix from btot, LDS 256-node histogram +
// scan -> offs/cnt/inv, then csr fill with LDS cursors. Stage entries packed.
__global__ __launch_bounds__(256) void bucket_fill2(
    const unsigned* __restrict__ stage, const int* __restrict__ btot,
    int* __restrict__ offs, int* __restrict__ cnt, float* __restrict__ inv,
    int* __restrict__ csr, int N) {
  __shared__ int lhist[256];
  __shared__ int lscan[256];
  __shared__ int lcur[256];
  __shared__ int red[256];
  const int b = blockIdx.x;
  const int t = threadIdx.x;
  int sum = 0;
  for (int j = t; j < b; j += 256) sum += btot[j];
  red[t] = sum;
  lhist[t] = 0;
  __syncthreads();
  for (int d = 128; d; d >>= 1) {
    if (t < d) red[t] += red[t + d];
    __syncthreads();
  }
  const int base = red[0];
  const int count = btot[b];
  const unsigned* sp = stage + (size_t)b * CAP;
  for (int i = t; i < count; i += 256)
    atomicAdd(&lhist[sp[i] & 255u], 1);
  __syncthreads();
  int v = lhist[t];
  lscan[t] = v;
  __syncthreads();
  for (int d = 1; d < 256; d <<= 1) {
    int tv = (t >= d) ? lscan[t - d] : 0;
    __syncthreads();
    lscan[t] += tv;
    __syncthreads();
  }
  const int excl = lscan[t] - v;
  const int node = b * 256 + t;
  if (node < N) {
    offs[node] = base + excl;
    cnt[node] = v;
    inv[node] = 1.0f / (float)((v > 1) ? v : 1);
  }
  lcur[t] = base + excl;
  __syncthreads();
  for (int i = t; i < count; i += 256) {
    unsigned sd = sp[i];
    int p = atomicAdd(&lcur[sd & 255u], 1);
    csr[p] = (int)(sd >> 8);
  }
}

// ---------------- mean-aggregate: M[n] = inv[n] * sum_{j in N(n)} A[j] ----------------
// Round-3 inner body (proven), now PERSISTENT: 2048 grid-striding blocks
// instead of 12500 one-shot blocks — steady ~8 blocks/CU residency removes
// the block-churn occupancy deficit (measured 60% -> target ~85%).
__global__ __launch_bounds__(256, 4) void agg_mean(
    const unsigned short* __restrict__ A, const float* __restrict__ inv,
    const int* __restrict__ offs, const int* __restrict__ cnt,
    const int* __restrict__ csr, unsigned short* __restrict__ M, int n,
    int nunits) {
  const int lane = threadIdx.x & 63;
  const int wave = threadIdx.x >> 6;
  const int g = lane >> 4;      // edge slot 0..3
  const int l = lane & 15;      // column chunk: columns l*8 .. l*8+7
  const char* Ab = (const char*)A + (size_t)l * 16;   // per-lane column base

  for (int u = blockIdx.x; u < nunits; u += gridDim.x) {
    const int pr = u * 4 + wave;
    const int n0 = pr * 2;
    if (n0 >= n) continue;
    const int n1 = n0 + 1;
    const bool has1 = (n1 < n);
    const int deg0 = cnt[n0];
    const int deg1 = has1 ? cnt[n1] : 0;
    const int start = offs[n0];
    const int T = deg0 + deg1;    // CSR rows adjacent -> combined segment
    f32x2 acc0[4] = {{0.f, 0.f}, {0.f, 0.f}, {0.f, 0.f}, {0.f, 0.f}};
    f32x2 acc1[4] = {{0.f, 0.f}, {0.f, 0.f}, {0.f, 0.f}, {0.f, 0.f}};

    if (T <= 64) {
      // byte offset of each neighbor row (idx*256); shfl the offset directly
      int offb = ((lane < T) ? csr[start + lane] : 0) << 8;
      {
        // chunk A: edges 0..31
        int nb2[8];
        uint4 vv[8];
#pragma unroll
        for (int j = 0; j < 8; ++j) nb2[j] = __shfl(offb, j * 4 + g);
#pragma unroll
        for (int j = 0; j < 8; ++j)
          vv[j] = *(const uint4*)(Ab + (size_t)(unsigned)nb2[j]);
#pragma unroll
        for (int j = 0; j < 8; ++j) {
          int e = j * 4 + g;
          if (e < deg0) addf2(acc0, vv[j]);
          else if (e < T) addf2(acc1, vv[j]);
        }
      }
      if (T > 32) {
        // chunk B: edges 32..63 (wave-uniform branch)
        int nb2[8];
        uint4 vv[8];
#pragma unroll
        for (int j = 0; j < 8; ++j) nb2[j] = __shfl(offb, 32 + j * 4 + g);
#pragma unroll
        for (int j = 0; j < 8; ++j)
          vv[j] = *(const uint4*)(Ab + (size_t)(unsigned)nb2[j]);
#pragma unroll
        for (int j = 0; j < 8; ++j) {
          int e = 32 + j * 4 + g;
          if (e < deg0) addf2(acc0, vv[j]);
          else if (e < T) addf2(acc1, vv[j]);
        }
      }
    } else {
      // rare generic path (T > 64 essentially never at mean degree 16)
      for (int node = 0; node < 2; ++node) {
        int dg = node ? deg1 : deg0;
        int st = node ? (start + deg0) : start;
        for (int base = 0; base < dg; base += 64) {
          int m = dg - base;
          if (m > 64) m = 64;
          int offb = ((lane < m) ? csr[st + base + lane] : 0) << 8;
#pragma unroll 4
          for (int i = 0; i < m; i += 4) {
            int sl = i + g;
            int nbv = __shfl(offb, sl & 63);  // full-exec shfl
            if (sl < m) {
              uint4 v = *(const uint4*)(Ab + (size_t)(unsigned)nbv);
              if (node) addf2(acc1, v);
              else addf2(acc0, v);
            }
          }
        }
      }
    }

    // reduce the 4 edge-slots (lanes differing in bits 4..5)
#pragma unroll
    for (int k = 0; k < 4; ++k) {
      acc0[k].x += __shfl_xor(acc0[k].x, 16);
      acc0[k].x += __shfl_xor(acc0[k].x, 32);
      acc0[k].y += __shfl_xor(acc0[k].y, 16);
      acc0[k].y += __shfl_xor(acc0[k].y, 32);
      acc1[k].x += __shfl_xor(acc1[k].x, 16);
      acc1[k].x += __shfl_xor(acc1[k].x, 32);
      acc1[k].y += __shfl_xor(acc1[k].y, 16);
      acc1[k].y += __shfl_xor(acc1[k].y, 32);
    }

    const int c0 = l * 8 + g * 2;
    {
      float s = inv[n0];
      unsigned pkt = (unsigned)f2bf(acc0[g].x * s) |
                     ((unsigned)f2bf(acc0[g].y * s) << 16);
      *(unsigned*)(M + (size_t)n0 * 128 + c0) = pkt;
    }
    if (has1) {
      float s = inv[n1];
      unsigned pkt = (unsigned)f2bf(acc1[g].x * s) |
                     ((unsigned)f2bf(acc1[g].y * s) << 16);
      *(unsigned*)(M + (size_t)n1 * 128 + c0) = pkt;
    }
  }
}

// ---------------- fused GEMM: out = Am@Wl^T + As@Wr^T + b (+relu) ----------------
// PERSISTENT: 64 KiB LDS caps residency at 2 blocks/CU anyway, so use 512
// grid-striding blocks that stage W ONCE (single barrier; W read-only after).
template <int RELU, int OUTBF>
__global__ __launch_bounds__(256) void gemm_fused(
    const unsigned short* __restrict__ Am,  // aggregated input -> Wl
    const unsigned short* __restrict__ As,  // self input -> Wr
    const unsigned short* __restrict__ Wp,  // [2*16384] bf16, fragment order
    const float* __restrict__ bias, void* __restrict__ outp, int n,
    int nchunks) {
  __shared__ unsigned short wsh[2 * 16384];  // 64 KiB
  const int tid = threadIdx.x;

  {
    const uint4* wsrc = (const uint4*)Wp;
    uint4* wdst = (uint4*)wsh;
#pragma unroll
    for (int it = 0; it < 16; ++it) {
      int id = it * 256 + tid;
      wdst[id] = wsrc[id];
    }
  }
  __syncthreads();

  const int lane = tid & 63;
  const int wave = tid >> 6;
  const int nn = lane & 15;
  const int quad = lane >> 4;

  for (int ch = blockIdx.x; ch < nchunks; ch += gridDim.x) {
    const int rowbase = ch * 64 + wave * 16;
    int nodeA = rowbase + nn;
    if (nodeA > n - 1) nodeA = n - 1;

    short8 am[4], asf[4];
#pragma unroll
    for (int s = 0; s < 4; ++s) {
      am[s] = *(const short8*)(Am + (size_t)nodeA * 128 + s * 32 + quad * 8);
      asf[s] = *(const short8*)(As + (size_t)nodeA * 128 + s * 32 + quad * 8);
    }

    f32x4 acc[8];
#pragma unroll
    for (int jt = 0; jt < 8; ++jt) acc[jt] = (f32x4){0.f, 0.f, 0.f, 0.f};

#pragma unroll
    for (int jt = 0; jt < 8; ++jt) {
#pragma unroll
      for (int s = 0; s < 4; ++s) {
        int c = (s * 8 + jt) * 4 + quad;
        short8 bl = *(const short8*)(wsh + (c * 16 + nn) * 8);
        short8 br = *(const short8*)(wsh + 16384 + (c * 16 + nn) * 8);
        acc[jt] = __builtin_amdgcn_mfma_f32_16x16x32_bf16(am[s], bl, acc[jt], 0, 0, 0);
        acc[jt] = __builtin_amdgcn_mfma_f32_16x16x32_bf16(asf[s], br, acc[jt], 0, 0, 0);
      }
    }

#pragma unroll
    for (int jt = 0; jt < 8; ++jt) {
      int col = jt * 16 + nn;
      float bv = bias[col];
#pragma unroll
      for (int r = 0; r < 4; ++r) {
        int ro = rowbase + quad * 4 + r;
        if (ro < n) {
          float o = acc[jt][r] + bv;
          if (RELU) o = fmaxf(o, 0.f);
          if (OUTBF) {
            ((unsigned short*)outp)[(size_t)ro * 128 + col] = f2bf(o);
          } else {
            ((float*)outp)[(size_t)ro * 128 + col] = o;
          }
        }
      }
    }
  }
}

// ---------------- launch ----------------
// Round-3 split structure (verified best; coop mega-fusion, in-kernel
// agg+gemm fusion, and deep gather prefetch all empirically refuted).
//   M = mean_agg(A); out = M@Wl^T + A@Wr^T + b
// Buffers: xb (bf16 x) lives in d_out (dead before final gemm writes it);
//          stage (packed 4B) / hb share a ws region.

extern "C" void kernel_launch(void* const* d_in, const int* in_sizes, int n_in,
                              void* d_out, int out_size, void* d_ws, size_t ws_size,
                              hipStream_t stream) {
  const float* x = (const float*)d_in[0];
  const int* ei = (const int*)d_in[1];
  const float* W1l = (const float*)d_in[2];
  const float* b1 = (const float*)d_in[3];
  const float* W1r = (const float*)d_in[4];
  const float* W2l = (const float*)d_in[5];
  const float* b2 = (const float*)d_in[6];
  const float* W2r = (const float*)d_in[7];
  float* out = (float*)d_out;

  const int N = in_sizes[0] / 128;
  const int E = in_sizes[1] / 2;
  const int nb = (N + 255) / 256;   // buckets of 256 nodes; must be <= NBMAX

  char* p = (char*)d_ws;
  auto alloc = [&](size_t bytes) {
    char* r = p;
    p += (bytes + 255) & ~(size_t)255;
    return r;
  };
  int* btot = (int*)alloc((size_t)NBMAX * 4);
  int* cnt = (int*)alloc((size_t)N * 4);
  int* offs = (int*)alloc((size_t)N * 4);
  float* inv = (float*)alloc((size_t)N * 4);
  int* csr = (int*)alloc((size_t)E * 4);
  unsigned short* Mb = (unsigned short*)alloc((size_t)N * 128 * 2);   // 25.6 MB
  unsigned short* Wpb = (unsigned short*)alloc((size_t)4 * 16384 * 2); // 128 KB
  size_t stage_bytes = (size_t)nb * CAP * 4;   // packed 4B entries
  size_t hb_bytes = (size_t)N * 128 * 2;
  char* shared_region = alloc(stage_bytes > hb_bytes ? stage_bytes : hb_bytes);
  unsigned short* hb = (unsigned short*)shared_region;  // h (bf16) after CSR done
  unsigned* stage = (unsigned*)shared_region;           // staging during CSR build

  // xb: bf16 cast of x, parked in d_out (only the last gemm writes d_out)
  unsigned short* xb = (unsigned short*)d_out;

  hipMemsetAsync(btot, 0, (size_t)nb * 4, stream);

  const int SB = (E + 4095) / 4096;
  prep<<<SB + 4 + 2048, 256, 0, stream>>>(ei, E, btot, stage, SB,
                                          x, xb, N * 128 / 8,
                                          W1l, W1r, W2l, W2r, Wpb);
  bucket_fill2<<<nb, 256, 0, stream>>>(stage, btot, offs, cnt, inv, csr, N);

  const int gb = (N + 63) / 64;
  const int PB = gb < 512 ? gb : 512;   // persistent gemm grid (2 blocks/CU)
  const int pairs = (N + 1) / 2;
  const int ab2 = (pairs + 3) / 4;      // pair-units of 4 pairs (1 block-quantum)
  const int AB = ab2 < 2048 ? ab2 : 2048;  // persistent agg grid (8 blocks/CU)

  // layer 1: M1 = mean_agg(xb); h = relu(M1@W1l^T + xb@W1r^T + b1) -> hb (bf16)
  agg_mean<<<AB, 256, 0, stream>>>(xb, inv, offs, cnt, csr, Mb, N, ab2);
  gemm_fused<1, 1><<<PB, 256, 0, stream>>>(Mb, xb, Wpb, b1, (void*)hb, N, gb);
  // layer 2: M2 = mean_agg(hb); out = M2@W2l^T + hb@W2r^T + b2 -> d_out (f32)
  agg_mean<<<AB, 256, 0, stream>>>(hb, inv, offs, cnt, csr, Mb, N, ab2);
  gemm_fused<0, 0><<<PB, 256, 0, stream>>>(Mb, hb, Wpb + 32768, b2, (void*)out, N, gb);
}